// Round 8
// baseline (1710.393 us; speedup 1.0000x reference)
//
#include <hip/hip_runtime.h>
#include <hip/hip_bf16.h>

typedef __attribute__((ext_vector_type(8))) short bf16x8;
typedef __attribute__((ext_vector_type(4))) float f32x4;

#define DEVI __device__ __forceinline__

DEVI short f2bf(float f) {
  union { float f; unsigned u; } v; v.f = f;
  unsigned r = v.u + 0x7FFFu + ((v.u >> 16) & 1u);
  return (short)(r >> 16);
}

DEVI float exp2a(float x) { float r; asm("v_exp_f32 %0, %1" : "=v"(r) : "v"(x)); return r; }

DEVI unsigned pk2(float lo, float hi) {
  union { __hip_bfloat162 h; unsigned u; } v;
  float2 f; f.x = lo; f.y = hi;
  v.h = __float22bfloat162_rn(f);
  return v.u;
}

union U8 { unsigned u[4]; bf16x8 v; };
DEVI bf16x8 mk8(unsigned a, unsigned b, unsigned c, unsigned d) {
  U8 x; x.u[0]=a; x.u[1]=b; x.u[2]=c; x.u[3]=d; return x.v;
}

#define MFMA __builtin_amdgcn_mfma_f32_16x16x32_bf16

// ---------------- pack kernels ----------------
// wPk fragment-linear for the per-head QKV GEMMs.
// slot = ((h*16+kf)*6 + s), s: 0,1 = Wq^T A-frag (mq=s), 2,3 = Wk^T A-frag,
// 4,5 = Wv B-frag (nv=s-4). Element: wPk[slot*512 + lane*8 + e] =
//   bf16( w_qkv[ c ][ (s>>1)*512 + h*32 + (s&1)*16 + (lane&15) ] ), c = kf*32+(lane>>4)*8+e.
__global__ __launch_bounds__(256) void pack_wqkv(const float* __restrict__ w,
                                                 short* __restrict__ wPk) {
  int i = blockIdx.x * 256 + threadIdx.x;      // 786432
  int e = i & 7, lane = (i >> 3) & 63;
  int slot = i >> 9;
  int s = slot % 6, q2 = slot / 6;
  int kf = q2 & 15, h = q2 >> 4;
  int g = lane >> 4, l15 = lane & 15;
  int c = kf * 32 + g * 8 + e;
  int col = (s >> 1) * 512 + h * 32 + (s & 1) * 16 + l15;
  wPk[i] = f2bf(w[c * 1536 + col]);
}

// wpPk: B-frag pack for proj: wpPk[(cf*16+kf)*512 + lane*8 + e] = bf16(w_proj[k][cf*16+(lane&15)])
__global__ __launch_bounds__(256) void pack_wproj(const float* __restrict__ w,
                                                  short* __restrict__ wpPk) {
  int i = blockIdx.x * 256 + threadIdx.x;      // 262144
  int e = i & 7, lane = (i >> 3) & 63, kf = (i >> 9) & 15, cf = i >> 13;
  int g = lane >> 4, l15 = lane & 15;
  int k = kf * 32 + g * 8 + e, col = cf * 16 + l15;
  wpPk[i] = f2bf(w[k * 512 + col]);
}

// biasT[h][m][n] = btab[relidx(n_query, m_key)*16+h] * log2(e); -1e30 for m>=49
__global__ __launch_bounds__(256) void fill_biasT(const float* __restrict__ btab,
                                                  float* __restrict__ biasT) {
  int i = blockIdx.x * 256 + threadIdx.x;      // 16*64*64
  int h = i >> 12, m = (i >> 6) & 63, n = i & 63;
  float v;
  if (m >= 49) {
    v = -1e30f;
  } else {
    int nn = n > 48 ? 48 : n;
    int ni = nn / 7, nj = nn - ni * 7;
    int mi = m / 7,  mj = m - mi * 7;
    int idx = (ni - mi + 6) * 13 + (nj - mj + 6);
    v = btab[idx * 16 + h] * 1.4426950408889634f;
  }
  biasT[i] = v;
}

// ---------------- megakernel v2: one block per window, zero-transpose dataflow ----------------
// Phase 1: x window (49x512 fp32->bf16, rows 49-63 := row 48) -> As [64][520] (padded rows).
// Phase 2 per wave (4 heads sequential): Q^T,K^T via transposed GEMM (A=W-frag, B=X-frag),
//   V via normal GEMM. C-layouts feed QK^T / PV fragments PURELY IN-LANE under
//   sigma(g,e) = 16*(e>>2) + 4g + (e&3). Swapped-QK^T in-register softmax (r3-verified).
// Phase 3: O -> As (x dead), proj GEMM, +b_proj -> out.

__global__ __launch_bounds__(256, 2)
void fusedwin(const float* __restrict__ x, const short* __restrict__ wPk,
              const short* __restrict__ wpPk, const float* __restrict__ bqkv,
              const float* __restrict__ bproj, const float* __restrict__ biasT,
              float* __restrict__ out) {
  __shared__ short As[64 * 520];   // 66,560 B

  const int t = threadIdx.x, lane = t & 63, wv = t >> 6;
  const int l15 = lane & 15, g = lane >> 4, g4 = g * 4;
  const int b = blockIdx.x;

  // ---- phase 1: stage x window
  {
    const float* xw = x + (long)b * 25088;
#pragma unroll
    for (int it = 0; it < 16; ++it) {
      int q = it * 256 + t, row = q >> 6, c = q & 63;
      int sr = row > 48 ? 48 : row;
      const float4* p = (const float4*)(xw + sr * 512 + c * 8);
      float4 a = p[0], d = p[1];
      bf16x8 r;
      r[0] = f2bf(a.x); r[1] = f2bf(a.y); r[2] = f2bf(a.z); r[3] = f2bf(a.w);
      r[4] = f2bf(d.x); r[5] = f2bf(d.y); r[6] = f2bf(d.z); r[7] = f2bf(d.w);
      *(bf16x8*)(As + row * 520 + c * 8) = r;
    }
  }
  __syncthreads();

  unsigned up[4][4][2][2];   // packed attn-out [hh][j][dt][rpair]

#pragma unroll
  for (int hh = 0; hh < 4; ++hh) {
    const int h = wv * 4 + hh;

    // per-lane biases
    float bQ[2][4], bK[2][4], bV[2];
#pragma unroll
    for (int mq = 0; mq < 2; ++mq)
#pragma unroll
      for (int r = 0; r < 4; ++r) {
        bQ[mq][r] = bqkv[h * 32 + mq * 16 + g4 + r];
        bK[mq][r] = bqkv[512 + h * 32 + mq * 16 + g4 + r];
      }
    bV[0] = bqkv[1024 + h * 32 + l15];
    bV[1] = bqkv[1024 + h * 32 + 16 + l15];

    // ---- QKV GEMMs (Q^T, K^T transposed; V normal), all share X-frags
    f32x4 aq[2][4] = {}, ak[2][4] = {}, av[4][2] = {};
    const short* wp = wPk + (long)((h * 16) * 6) * 512 + lane * 8;
#pragma unroll
    for (int kf = 0; kf < 16; ++kf) {
      bf16x8 af[4], wf[6];
#pragma unroll
      for (int nf = 0; nf < 4; ++nf)
        af[nf] = *(const bf16x8*)(As + (nf * 16 + l15) * 520 + kf * 32 + g * 8);
#pragma unroll
      for (int s = 0; s < 6; ++s)
        wf[s] = *(const bf16x8*)(wp + (long)(kf * 6 + s) * 512);
#pragma unroll
      for (int mq = 0; mq < 2; ++mq)
#pragma unroll
        for (int nf = 0; nf < 4; ++nf) {
          aq[mq][nf] = MFMA(wf[mq], af[nf], aq[mq][nf], 0, 0, 0);
          ak[mq][nf] = MFMA(wf[2 + mq], af[nf], ak[mq][nf], 0, 0, 0);
        }
#pragma unroll
      for (int mf = 0; mf < 4; ++mf)
#pragma unroll
        for (int nv = 0; nv < 2; ++nv)
          av[mf][nv] = MFMA(af[mf], wf[4 + nv], av[mf][nv], 0, 0, 0);
    }

    // ---- in-lane packs: Q/K A/B-frags under sigma; V B-frags under 32kt+sigma
    bf16x8 qf[4], kfr[4];
#pragma unroll
    for (int i2 = 0; i2 < 4; ++i2) {
      qf[i2]  = mk8(pk2(aq[0][i2][0] + bQ[0][0], aq[0][i2][1] + bQ[0][1]),
                    pk2(aq[0][i2][2] + bQ[0][2], aq[0][i2][3] + bQ[0][3]),
                    pk2(aq[1][i2][0] + bQ[1][0], aq[1][i2][1] + bQ[1][1]),
                    pk2(aq[1][i2][2] + bQ[1][2], aq[1][i2][3] + bQ[1][3]));
      kfr[i2] = mk8(pk2(ak[0][i2][0] + bK[0][0], ak[0][i2][1] + bK[0][1]),
                    pk2(ak[0][i2][2] + bK[0][2], ak[0][i2][3] + bK[0][3]),
                    pk2(ak[1][i2][0] + bK[1][0], ak[1][i2][1] + bK[1][1]),
                    pk2(ak[1][i2][2] + bK[1][2], ak[1][i2][3] + bK[1][3]));
    }
    bf16x8 vf[2][2];
#pragma unroll
    for (int kt = 0; kt < 2; ++kt)
#pragma unroll
      for (int nv = 0; nv < 2; ++nv)
        vf[kt][nv] = mk8(pk2(av[2 * kt][nv][0] + bV[nv], av[2 * kt][nv][1] + bV[nv]),
                         pk2(av[2 * kt][nv][2] + bV[nv], av[2 * kt][nv][3] + bV[nv]),
                         pk2(av[2 * kt + 1][nv][0] + bV[nv], av[2 * kt + 1][nv][1] + bV[nv]),
                         pk2(av[2 * kt + 1][nv][2] + bV[nv], av[2 * kt + 1][nv][3] + bV[nv]));

    // ---- S = K.Q^T (swapped)
    f32x4 s[4][4] = {};
#pragma unroll
    for (int i2 = 0; i2 < 4; ++i2)
#pragma unroll
      for (int j = 0; j < 4; ++j)
        s[i2][j] = MFMA(kfr[i2], qf[j], s[i2][j], 0, 0, 0);

    // ---- softmax over keys (in-lane + 2 shfl)
    const float* biasH = biasT + h * 4096;
    float sum[4] = {0.f, 0.f, 0.f, 0.f};
#pragma unroll
    for (int i2 = 0; i2 < 4; ++i2)
#pragma unroll
      for (int r = 0; r < 4; ++r) {
        int m = i2 * 16 + g4 + r;
        const float* bp = biasH + m * 64 + l15;
#pragma unroll
        for (int j = 0; j < 4; ++j) {
          float p = exp2a(fmaf(s[i2][j][r], 0.06375871f, bp[j * 16]));
          s[i2][j][r] = p;
          sum[j] += p;
        }
      }
#pragma unroll
    for (int j = 0; j < 4; ++j) {
      sum[j] += __shfl_xor(sum[j], 16);
      sum[j] += __shfl_xor(sum[j], 32);
      sum[j] = 1.f / sum[j];
    }

    unsigned pk[4][4][2];
#pragma unroll
    for (int j = 0; j < 4; ++j)
#pragma unroll
      for (int i2 = 0; i2 < 4; ++i2) {
        pk[j][i2][0] = pk2(s[i2][j][0] * sum[j], s[i2][j][1] * sum[j]);
        pk[j][i2][1] = pk2(s[i2][j][2] * sum[j], s[i2][j][3] * sum[j]);
      }

    // ---- O = P.V
    f32x4 o[4][2] = {};
#pragma unroll
    for (int j = 0; j < 4; ++j) {
      bf16x8 a0 = mk8(pk[j][0][0], pk[j][0][1], pk[j][1][0], pk[j][1][1]);
      bf16x8 a1 = mk8(pk[j][2][0], pk[j][2][1], pk[j][3][0], pk[j][3][1]);
      o[j][0] = MFMA(a0, vf[0][0], o[j][0], 0, 0, 0);
      o[j][0] = MFMA(a1, vf[1][0], o[j][0], 0, 0, 0);
      o[j][1] = MFMA(a0, vf[0][1], o[j][1], 0, 0, 0);
      o[j][1] = MFMA(a1, vf[1][1], o[j][1], 0, 0, 0);
    }
#pragma unroll
    for (int j = 0; j < 4; ++j)
#pragma unroll
      for (int dt = 0; dt < 2; ++dt) {
        up[hh][j][dt][0] = pk2(o[j][dt][0], o[j][dt][1]);
        up[hh][j][dt][1] = pk2(o[j][dt][2], o[j][dt][3]);
      }
  }

  __syncthreads();   // all waves done reading x from As

  // ---- attn-out -> As rows [64][520]
#pragma unroll
  for (int hh = 0; hh < 4; ++hh) {
    int h = wv * 4 + hh;
#pragma unroll
    for (int j = 0; j < 4; ++j)
#pragma unroll
      for (int dt = 0; dt < 2; ++dt) {
        int col = h * 32 + dt * 16 + l15;
#pragma unroll
        for (int rp = 0; rp < 2; ++rp) {
          unsigned v = up[hh][j][dt][rp];
          int row0 = j * 16 + g4 + rp * 2;
          As[row0 * 520 + col] = (short)(v & 0xFFFFu);
          As[(row0 + 1) * 520 + col] = (short)(v >> 16);
        }
      }
  }
  __syncthreads();

  // ---- proj GEMM: wave owns cols wv*128..+127
  f32x4 a2[4][8] = {};
  const short* wpp = wpPk + (long)(wv * 128) * 512 + lane * 8;
#pragma unroll
  for (int kf = 0; kf < 16; ++kf) {
    bf16x8 af2[4], wf2[8];
#pragma unroll
    for (int mf = 0; mf < 4; ++mf)
      af2[mf] = *(const bf16x8*)(As + (mf * 16 + l15) * 520 + kf * 32 + g * 8);
#pragma unroll
    for (int nf = 0; nf < 8; ++nf)
      wf2[nf] = *(const bf16x8*)(wpp + (long)(nf * 16 + kf) * 512);
#pragma unroll
    for (int mf = 0; mf < 4; ++mf)
#pragma unroll
      for (int nf = 0; nf < 8; ++nf)
        a2[mf][nf] = MFMA(af2[mf], wf2[nf], a2[mf][nf], 0, 0, 0);
  }

  float* ob = out + (long)b * 25088;
#pragma unroll
  for (int mf = 0; mf < 4; ++mf)
#pragma unroll
    for (int r = 0; r < 4; ++r) {
      int row = mf * 16 + g4 + r;
      if (row < 49) {
#pragma unroll
        for (int nf = 0; nf < 8; ++nf) {
          int col = wv * 128 + nf * 16 + l15;
          ob[row * 512 + col] = a2[mf][nf][r] + bproj[col];
        }
      }
    }
}

// ---------------- host ----------------

extern "C" void kernel_launch(void* const* d_in, const int* in_sizes, int n_in,
                              void* d_out, int out_size, void* d_ws, size_t ws_size,
                              hipStream_t stream) {
  (void)in_sizes; (void)n_in; (void)out_size; (void)ws_size;
  const float* x      = (const float*)d_in[0];
  const float* w_qkv  = (const float*)d_in[1];
  const float* b_qkv  = (const float*)d_in[2];
  const float* w_proj = (const float*)d_in[3];
  const float* b_proj = (const float*)d_in[4];
  const float* btab   = (const float*)d_in[5];

  char* ws = (char*)d_ws;
  short* wPk   = (short*)ws;                        // 1,572,864 B
  short* wpPk  = (short*)(ws + 1572864L);           //   524,288 B
  float* biasT = (float*)(ws + 1572864L + 524288L); //   262,144 B

  pack_wqkv <<<3072, 256, 0, stream>>>(w_qkv, wPk);
  pack_wproj<<<1024, 256, 0, stream>>>(w_proj, wpPk);
  fill_biasT<<<256, 256, 0, stream>>>(btab, biasT);
  fusedwin  <<<4096, 256, 0, stream>>>(x, wPk, wpPk, b_qkv, b_proj, biasT,
                                       (float*)d_out);
}

// Round 9
// 881.432 us; speedup vs baseline: 1.9405x; 1.9405x over previous
//
#include <hip/hip_runtime.h>
#include <hip/hip_bf16.h>

typedef __attribute__((ext_vector_type(8))) short bf16x8;
typedef __attribute__((ext_vector_type(4))) float f32x4;

#define DEVI __device__ __forceinline__

DEVI short f2bf(float f) {
  union { float f; unsigned u; } v; v.f = f;
  unsigned r = v.u + 0x7FFFu + ((v.u >> 16) & 1u);
  return (short)(r >> 16);
}

DEVI void gl16(const void* g, void* l) {
  __builtin_amdgcn_global_load_lds((const __attribute__((address_space(1))) unsigned*)g,
                                   (__attribute__((address_space(3))) unsigned*)l,
                                   16, 0, 0);
}

DEVI float exp2a(float x) { float r; asm("v_exp_f32 %0, %1" : "=v"(r) : "v"(x)); return r; }

DEVI unsigned pk2(float lo, float hi) {
  union { __hip_bfloat162 h; unsigned u; } v;
  float2 f; f.x = lo; f.y = hi;
  v.h = __float22bfloat162_rn(f);
  return v.u;
}

union U8 { unsigned u[4]; bf16x8 v; };
DEVI bf16x8 mk8(unsigned a, unsigned b, unsigned c, unsigned d) {
  U8 x; x.u[0]=a; x.u[1]=b; x.u[2]=c; x.u[3]=d; return x.v;
}

// ---------------- conversion / prep kernels ----------------

__global__ __launch_bounds__(256) void conv_x_k(const float* __restrict__ x,
                                                short* __restrict__ xb) {
  long i = (long)blockIdx.x * 256 + threadIdx.x;
  const float4* xf = (const float4*)x;
  float4 a = xf[i * 2], c = xf[i * 2 + 1];
  bf16x8 r;
  r[0] = f2bf(a.x); r[1] = f2bf(a.y); r[2] = f2bf(a.z); r[3] = f2bf(a.w);
  r[4] = f2bf(c.x); r[5] = f2bf(c.y); r[6] = f2bf(c.z); r[7] = f2bf(c.w);
  *(bf16x8*)(xb + i * 8) = r;
}

// merged: wqT pack (blocks 0..3071), wpT pack (3072..4095), biasT fill (4096..4351)
__global__ __launch_bounds__(256) void prep_k(const float* __restrict__ wq,
                                              const float* __restrict__ wp,
                                              const float* __restrict__ btab,
                                              short* __restrict__ wqT,
                                              short* __restrict__ wpT,
                                              float* __restrict__ biasT) {
  int bid = blockIdx.x;
  if (bid < 3072) {
    int i = bid * 256 + threadIdx.x;            // 1536*512
    int n = i >> 9, k = i & 511;
    wqT[i] = f2bf(wq[k * 1536 + n]);
  } else if (bid < 4096) {
    int i = (bid - 3072) * 256 + threadIdx.x;   // 512*512
    int n = i >> 9, k = i & 511;
    wpT[i] = f2bf(wp[k * 512 + n]);
  } else {
    int i = (bid - 4096) * 256 + threadIdx.x;   // 16*64*64
    int h = i >> 12, m = (i >> 6) & 63, n = i & 63;
    float v;
    if (m >= 49) {
      v = -1e30f;
    } else {
      int nn = n > 48 ? 48 : n;
      int ni = nn / 7, nj = nn - ni * 7;
      int mi = m / 7,  mj = m - mi * 7;
      int idx = (ni - mi + 6) * 13 + (nj - mj + 6);
      v = btab[idx * 16 + h] * 1.4426950408889634f;
    }
    biasT[i] = v;
  }
}

// ---------------- 256x256 bf16 GEMM, BK=64, 4-phase counted-vmcnt schedule ----------------
// (r6-verified schedule.) EPI 0: qkv epilogue now bounces acc through LDS (free after
// K-loop) -> 16 coalesced dwordx4 stores/thread instead of 128 scalar b16 stores.

template <int EPI>
__global__ __launch_bounds__(512, 2)
void gemm256(const short* __restrict__ A, const short* __restrict__ Bt,
             const float* __restrict__ bias, void* __restrict__ outp, int ctiles) {
  __shared__ short Ls[65536];

  const int nwg = gridDim.x;
  const int w = blockIdx.x;
  const int chunk = nwg >> 3;
  const int tid = (w & 7) * chunk + (w >> 3);    // XCD-contiguous remap (nwg%8==0)
  const int rt = tid / ctiles, ct = tid % ctiles;
  const long m0 = (long)rt * 256;
  const int n0 = ct * 256;

  const int t = threadIdx.x;          // 0..511
  const int lane = t & 63;
  const int wv = t >> 6;
  const int wr = wv >> 2;             // 0..1  (M half)
  const int wc = wv & 3;              // 0..3  (N quarter)
  const int l15 = lane & 15, g = lane >> 4, g4 = g * 4;

  const int gch = (t & 3) ^ ((t >> 3) & 3);
  const short* Ag = A + (m0 + (t >> 2)) * 512 + gch * 8;
  const short* Bg = Bt + (long)(n0 + (t >> 2)) * 512 + gch * 8;

  const int cA = ((g ^ ((l15 >> 1) & 3))) * 8;
  const int rowA = (wr * 128 + l15) * 32;
  const int rowB = (wc * 64 + l15) * 32;

  f32x4 acc[8][4] = {};
  bf16x8 af[8], bfr[2];

#define STAGE_A(ktn, kh, bufn)                                         \
  { const short* s_ = Ag + (ktn) * 64 + (kh) * 32;                     \
    short* d_ = (bufn) + (kh) * 8192 + t * 8;                          \
    gl16(s_, d_); gl16(s_ + 128 * 512, d_ + 4096); }
#define STAGE_B(ktn, kh, bufn)                                         \
  { const short* s_ = Bg + (ktn) * 64 + (kh) * 32;                     \
    short* d_ = (bufn) + 16384 + (kh) * 8192 + t * 8;                  \
    gl16(s_, d_); gl16(s_ + 128 * 512, d_ + 4096); }
#define LOAD_AF(Ab, kh)                                                \
  _Pragma("unroll")                                                    \
  for (int mf = 0; mf < 8; ++mf)                                       \
    af[mf] = *(const bf16x8*)((Ab) + (kh) * 8192 + rowA + mf * 512 + cA);
#define LOAD_BF(Ab, kh, nh)                                            \
  bfr[0] = *(const bf16x8*)((Ab) + 16384 + (kh) * 8192 + rowB + ((nh) * 2) * 512 + cA); \
  bfr[1] = *(const bf16x8*)((Ab) + 16384 + (kh) * 8192 + rowB + ((nh) * 2 + 1) * 512 + cA);
#define MFMA16(nh)                                                     \
  __builtin_amdgcn_s_setprio(1);                                       \
  _Pragma("unroll")                                                    \
  for (int mf = 0; mf < 8; ++mf) {                                     \
    acc[mf][(nh) * 2] = __builtin_amdgcn_mfma_f32_16x16x32_bf16(af[mf], bfr[0], acc[mf][(nh) * 2], 0, 0, 0);         \
    acc[mf][(nh) * 2 + 1] = __builtin_amdgcn_mfma_f32_16x16x32_bf16(af[mf], bfr[1], acc[mf][(nh) * 2 + 1], 0, 0, 0); \
  }                                                                    \
  __builtin_amdgcn_s_setprio(0);
#define BAR() asm volatile("s_barrier" ::: "memory")
#define VMW4() asm volatile("s_waitcnt vmcnt(4)" ::: "memory")

  STAGE_A(0, 0, Ls); STAGE_B(0, 0, Ls); STAGE_A(0, 1, Ls); STAGE_B(0, 1, Ls);
  VMW4();
  BAR();

  for (int kt = 0; kt < 8; ++kt) {
    const short* Ab = Ls + (kt & 1) * 32768;
    short* Bn = Ls + ((kt & 1) ^ 1) * 32768;
    const int ktn = kt < 7 ? kt + 1 : 7;   // last tile: re-stage (dead buf, valid addrs)

    LOAD_AF(Ab, 0); LOAD_BF(Ab, 0, 0);
    STAGE_A(ktn, 0, Bn);
    BAR(); MFMA16(0); BAR();

    LOAD_BF(Ab, 0, 1);
    STAGE_B(ktn, 0, Bn);
    VMW4();
    BAR(); MFMA16(1); BAR();

    LOAD_AF(Ab, 1); LOAD_BF(Ab, 1, 0);
    STAGE_A(ktn, 1, Bn);
    BAR(); MFMA16(0); BAR();

    LOAD_BF(Ab, 1, 1);
    STAGE_B(ktn, 1, Bn);
    VMW4();
    BAR(); MFMA16(1); BAR();
  }

  if (EPI == 0) {
    // drain dangling restage DMA + all LDS reads, then reuse Ls as a 256x256 bf16 tile
    __syncthreads();
#pragma unroll
    for (int mf = 0; mf < 8; ++mf)
#pragma unroll
      for (int r = 0; r < 4; ++r) {
        int lrow = wr * 128 + mf * 16 + g4 + r;
#pragma unroll
        for (int nf = 0; nf < 4; ++nf) {
          int lcol = wc * 64 + nf * 16 + l15;
          Ls[lrow * 256 + lcol] = f2bf(acc[mf][nf][r] + bias[n0 + lcol]);
        }
      }
    __syncthreads();
    short* qkv = (short*)outp;
    const int cq = n0 >> 8;          // 0..5
    const int ii = cq >> 1;
#pragma unroll
    for (int s = 0; s < 16; ++s) {
      int c = s * 512 + t;
      int row = c >> 5, sub = c & 31;
      int hl = sub >> 2, d0 = (sub & 3) * 8;
      int rg = (int)m0 + row;
      int b = rg / 49, n = rg - b * 49;
      int h = (cq & 1) * 8 + hl;
      long dst = (long)((b * 16 + h) * 3 + ii) * 1568 + n * 32 + d0;
      *(bf16x8*)(qkv + dst) = *(const bf16x8*)(Ls + row * 256 + hl * 32 + d0);
    }
  } else {
    __syncthreads();   // drain dangling restage DMA before exit path
    float* out = (float*)outp;
#pragma unroll
    for (int mf = 0; mf < 8; ++mf)
#pragma unroll
      for (int r = 0; r < 4; ++r) {
        long row = m0 + wr * 128 + mf * 16 + g4 + r;
#pragma unroll
        for (int nf = 0; nf < 4; ++nf) {
          int col = n0 + wc * 64 + nf * 16 + l15;
          out[row * 512 + col] = acc[mf][nf][r] + bias[col];
        }
      }
  }
#undef STAGE_A
#undef STAGE_B
#undef LOAD_AF
#undef LOAD_BF
#undef MFMA16
#undef BAR
#undef VMW4
}

// ---------------- attention: swapped-QK^T, in-register softmax ----------------
// V now staged to wave-private LDS via 4 b128 loads (was 32 scalar global gathers).

__global__ __launch_bounds__(256, 3)
void attn49(const short* __restrict__ qkvb, const float* __restrict__ biasT,
            short* __restrict__ ao) {
  __shared__ short Vl[4][2048];   // 4 KB per wave, wave-private

  const int t = threadIdx.x, lane = t & 63, wv = t >> 6;
  const int l15 = lane & 15, g = lane >> 4, g4 = g * 4;
  const int b = blockIdx.x >> 2;
  const int h = (blockIdx.x & 3) * 4 + wv;

  const short* qb = qkvb + (long)(b * 16 + h) * 3 * 1568;
  const short* kb = qb + 1568;
  const short* vb = kb + 1568;
  short* Vs = Vl[wv];

  // stage V (1568 shorts = 196 x 8-short chunks; clamp tail -> duplicate same data)
#pragma unroll
  for (int it = 0; it < 4; ++it) {
    int c = it * 64 + lane; c = c > 195 ? 195 : c;
    *(bf16x8*)(Vs + c * 8) = *(const bf16x8*)(vb + c * 8);
  }

  // Q/K fragments (rows clamped to 48; junk killed by bias)
  bf16x8 qf[4], kf[4];
#pragma unroll
  for (int i = 0; i < 4; ++i) {
    int row = i * 16 + l15; row = row > 48 ? 48 : row;
    kf[i] = *(const bf16x8*)(kb + row * 32 + g * 8);
    qf[i] = *(const bf16x8*)(qb + row * 32 + g * 8);
  }

  // S = K·Q^T (swapped): rows m = key, cols n = query
  f32x4 s[4][4] = {};
#pragma unroll
  for (int i = 0; i < 4; ++i)
#pragma unroll
    for (int j = 0; j < 4; ++j)
      s[i][j] = __builtin_amdgcn_mfma_f32_16x16x32_bf16(kf[i], qf[j], s[i][j], 0, 0, 0);

  // V B-fragments from LDS: vf[kt][dt][e] = V[sigma(kt,g,e)][dt*16+l15], clamped
  bf16x8 vf[2][2];
#pragma unroll
  for (int kt = 0; kt < 2; ++kt)
#pragma unroll
    for (int hi = 0; hi < 2; ++hi)
#pragma unroll
      for (int r = 0; r < 4; ++r) {
        int m = kt * 32 + hi * 16 + g4 + r;
        m = m > 48 ? 48 : m;
#pragma unroll
        for (int dt = 0; dt < 2; ++dt)
          vf[kt][dt][hi * 4 + r] = Vs[m * 32 + dt * 16 + l15];
      }

  // p = exp2(s*scale*log2e + biasT); column sums (over m) in-lane + 2 shfl
  const float* biasH = biasT + h * 4096;
  float sum[4] = {0.f, 0.f, 0.f, 0.f};
#pragma unroll
  for (int i = 0; i < 4; ++i)
#pragma unroll
    for (int r = 0; r < 4; ++r) {
      int m = i * 16 + g4 + r;
      const float* bp = biasH + m * 64 + l15;
#pragma unroll
      for (int j = 0; j < 4; ++j) {
        float p = exp2a(fmaf(s[i][j][r], 0.06375871f, bp[j * 16]));
        s[i][j][r] = p;
        sum[j] += p;
      }
    }
#pragma unroll
  for (int j = 0; j < 4; ++j) {
    sum[j] += __shfl_xor(sum[j], 16);
    sum[j] += __shfl_xor(sum[j], 32);
    sum[j] = 1.f / sum[j];
  }

  unsigned pk[4][4][2];
#pragma unroll
  for (int j = 0; j < 4; ++j)
#pragma unroll
    for (int i = 0; i < 4; ++i) {
      pk[j][i][0] = pk2(s[i][j][0] * sum[j], s[i][j][1] * sum[j]);
      pk[j][i][1] = pk2(s[i][j][2] * sum[j], s[i][j][3] * sum[j]);
    }

  // O = P·V
  f32x4 o[4][2] = {};
#pragma unroll
  for (int j = 0; j < 4; ++j) {
    bf16x8 a0 = mk8(pk[j][0][0], pk[j][0][1], pk[j][1][0], pk[j][1][1]);
    bf16x8 a1 = mk8(pk[j][2][0], pk[j][2][1], pk[j][3][0], pk[j][3][1]);
    o[j][0] = __builtin_amdgcn_mfma_f32_16x16x32_bf16(a0, vf[0][0], o[j][0], 0, 0, 0);
    o[j][0] = __builtin_amdgcn_mfma_f32_16x16x32_bf16(a1, vf[1][0], o[j][0], 0, 0, 0);
    o[j][1] = __builtin_amdgcn_mfma_f32_16x16x32_bf16(a0, vf[0][1], o[j][1], 0, 0, 0);
    o[j][1] = __builtin_amdgcn_mfma_f32_16x16x32_bf16(a1, vf[1][1], o[j][1], 0, 0, 0);
  }

  // write attn_out [M,512] bf16: col = h*32 + d
#pragma unroll
  for (int j = 0; j < 4; ++j)
#pragma unroll
    for (int r = 0; r < 4; ++r) {
      int n = j * 16 + g4 + r;
      if (n < 49) {
        long off = ((long)b * 49 + n) * 512 + h * 32 + l15;
        ao[off]      = f2bf(o[j][0][r]);
        ao[off + 16] = f2bf(o[j][1][r]);
      }
    }
}

// ---------------- host ----------------

extern "C" void kernel_launch(void* const* d_in, const int* in_sizes, int n_in,
                              void* d_out, int out_size, void* d_ws, size_t ws_size,
                              hipStream_t stream) {
  (void)in_sizes; (void)n_in; (void)ws_size;
  const float* x      = (const float*)d_in[0];
  const float* w_qkv  = (const float*)d_in[1];
  const float* b_qkv  = (const float*)d_in[2];
  const float* w_proj = (const float*)d_in[3];
  const float* b_proj = (const float*)d_in[4];
  const float* btab   = (const float*)d_in[5];

  char* ws = (char*)d_ws;
  short* xb  = (short*)ws;                                        // 205,520,896 B
  short* wqT = (short*)(ws + 205520896L);                         //   1,572,864 B
  short* wpT = (short*)(ws + 205520896L + 1572864L);              //     524,288 B
  short* qkv = (short*)(ws + 205520896L + 1572864L + 524288L);    // 616,562,688 B
  short* ao  = xb;                     // alias: x_bf16 dead after QKV GEMM
  // biasT lives in the tail of d_out: written by prep_k, read by attn49, then fully
  // overwritten by the proj GEMM before validation (proj writes every output element).
  float* biasT = (float*)d_out + (out_size - 65536);

  conv_x_k<<<50176, 256, 0, stream>>>(x, xb);
  prep_k  <<<4352, 256, 0, stream>>>(w_qkv, w_proj, btab, wqT, wpT, biasT);
  gemm256<0><<<4704, 512, 0, stream>>>(xb, wqT, b_qkv, (void*)qkv, 6);
  attn49  <<<16384, 256, 0, stream>>>(qkv, biasT, ao);
  gemm256<1><<<1568, 512, 0, stream>>>(ao, wpT, b_proj, d_out, 2);
}

// Round 10
// 853.672 us; speedup vs baseline: 2.0036x; 1.0325x over previous
//
#include <hip/hip_runtime.h>
#include <hip/hip_bf16.h>

typedef __attribute__((ext_vector_type(8))) short bf16x8;
typedef __attribute__((ext_vector_type(4))) float f32x4;

#define DEVI __device__ __forceinline__
#define MFMA __builtin_amdgcn_mfma_f32_16x16x32_bf16

DEVI short f2bf(float f) {
  union { float f; unsigned u; } v; v.f = f;
  unsigned r = v.u + 0x7FFFu + ((v.u >> 16) & 1u);
  return (short)(r >> 16);
}

DEVI float exp2a(float x) { float r; asm("v_exp_f32 %0, %1" : "=v"(r) : "v"(x)); return r; }

DEVI unsigned pk2(float lo, float hi) {
  union { __hip_bfloat162 h; unsigned u; } v;
  float2 f; f.x = lo; f.y = hi;
  v.h = __float22bfloat162_rn(f);
  return v.u;
}

union U8 { unsigned u[4]; bf16x8 v; };
DEVI bf16x8 mk8(unsigned a, unsigned b, unsigned c, unsigned d) {
  U8 x; x.u[0]=a; x.u[1]=b; x.u[2]=c; x.u[3]=d; return x.v;
}

// ---------------- prep: fragment-linear weight packs + biasT ----------------
// wqP[((cf*16+kc)*512 + lane*8 + e] = bf16(wq[k][col]); k = kc*32+(lane>>4)*8+e,
// col = cf*16+(lane&15).  wpP same from w_proj.  biasT as before.
__global__ __launch_bounds__(256) void prep_k(const float* __restrict__ wq,
                                              const float* __restrict__ wp,
                                              const float* __restrict__ btab,
                                              short* __restrict__ wqP,
                                              short* __restrict__ wpP,
                                              float* __restrict__ biasT) {
  int bid = blockIdx.x;
  if (bid < 4096) {
    int i = (bid < 3072 ? bid : bid - 3072) * 256 + threadIdx.x;
    int e = i & 7, lane = (i >> 3) & 63, kc = (i >> 9) & 15, cf = i >> 13;
    int k = kc * 32 + (lane >> 4) * 8 + e;
    int col = cf * 16 + (lane & 15);
    if (bid < 3072) wqP[i] = f2bf(wq[k * 1536 + col]);
    else            wpP[i] = f2bf(wp[k * 512 + col]);
  } else {
    int i = (bid - 4096) * 256 + threadIdx.x;   // 16*64*64
    int h = i >> 12, m = (i >> 6) & 63, n = i & 63;
    float v;
    if (m >= 49) {
      v = -1e30f;
    } else {
      int nn = n > 48 ? 48 : n;
      int ni = nn / 7, nj = nn - ni * 7;
      int mi = m / 7,  mj = m - mi * 7;
      int idx = (ni - mi + 6) * 13 + (nj - mj + 6);
      v = btab[idx * 16 + h] * 1.4426950408889634f;
    }
    biasT[i] = v;
  }
}

// ---------------- 256x256 bf16 GEMM: A reg-staged (opt. fp32->bf16 fused), ----------------
// B-frags direct from packed global (L1/L2-resident), LDS holds A only (64KB dbuf).
// One barrier per K-tile; per-load compiler vmcnt waits keep staging in flight.

template <int EPI, bool AF32>
__global__ __launch_bounds__(512)
void gemm256(const void* __restrict__ Ap, const short* __restrict__ wB,
             const float* __restrict__ bias, void* __restrict__ outp, int ctiles) {
  __shared__ short Ls[65536];   // K-loop: [2][16384] A dbuf; EPI0 epilogue: full 128KB

  const int nwg = gridDim.x;
  const int w = blockIdx.x;
  const int chunk = nwg >> 3;
  const int tid = (w & 7) * chunk + (w >> 3);    // XCD-contiguous remap (nwg%8==0)
  const int rt = tid / ctiles, ct = tid % ctiles;
  const long m0 = (long)rt * 256;
  const int n0 = ct * 256;

  const int t = threadIdx.x;          // 0..511
  const int lane = t & 63;
  const int wv = t >> 6;
  const int wr = wv >> 2;             // M half
  const int wc = wv & 3;              // N quarter
  const int l15 = lane & 15, g = lane >> 4, g4 = g * 4;

  // A staging: thread t -> LDS row t>>2 (+128), 16B slot t&3, global chunk swizzled
  const int gch = (t & 3) ^ ((t >> 3) & 3);
  const float* Agf = (const float*)Ap + (m0 + (t >> 2)) * 512 + gch * 8;
  const short* Agh = (const short*)Ap + (m0 + (t >> 2)) * 512 + gch * 8;

  const int cA = (g ^ ((l15 >> 1) & 3)) * 8;
  const int rowA = (wr * 128 + l15) * 32;

  // B frags: cf = ct*16 + wc*4 + nf ; addr = wB + (cf*16 + kc)*512 + lane*8
  const short* wBb = wB + ((long)(ct * 16 + wc * 4) << 13) + lane * 8;

  f32x4 acc[8][4] = {};
  bf16x8 af[8];
  bf16x8 bP[4][2];
  float4 ga[4][2];
  bf16x8 gb[4];

#define ISSUE_A(ktn)                                                          \
  if (AF32) {                                                                 \
    _Pragma("unroll")                                                         \
    for (int c = 0; c < 4; ++c) {                                             \
      const float* s_ = Agf + (c >> 1) * 65536 + (c & 1) * 32 + (ktn) * 64;   \
      ga[c][0] = *(const float4*)s_;                                          \
      ga[c][1] = *(const float4*)(s_ + 4);                                    \
    }                                                                         \
  } else {                                                                    \
    _Pragma("unroll")                                                         \
    for (int c = 0; c < 4; ++c)                                               \
      gb[c] = *(const bf16x8*)(Agh + (c >> 1) * 65536 + (c & 1) * 32 + (ktn) * 64); \
  }
#define WRITE_A(nb)                                                           \
  _Pragma("unroll")                                                           \
  for (int c = 0; c < 4; ++c) {                                               \
    short* d_ = (nb) + (c & 1) * 8192 + (c >> 1) * 4096 + t * 8;              \
    if (AF32) {                                                               \
      *(bf16x8*)d_ = mk8(pk2(ga[c][0].x, ga[c][0].y), pk2(ga[c][0].z, ga[c][0].w), \
                         pk2(ga[c][1].x, ga[c][1].y), pk2(ga[c][1].z, ga[c][1].w)); \
    } else {                                                                  \
      *(bf16x8*)d_ = gb[c];                                                   \
    }                                                                         \
  }
#define LOAD_BP(p, ktn)                                                       \
  bP[p][0] = *(const bf16x8*)(wBb + ((((((p) & 1) * 2 + 0) * 16 + ((ktn) * 2 + ((p) >> 1)))) << 9)); \
  bP[p][1] = *(const bf16x8*)(wBb + ((((((p) & 1) * 2 + 1) * 16 + ((ktn) * 2 + ((p) >> 1)))) << 9));
#define LOAD_AF(buf, kh)                                                      \
  _Pragma("unroll")                                                           \
  for (int mf = 0; mf < 8; ++mf)                                              \
    af[mf] = *(const bf16x8*)((buf) + (kh) * 8192 + rowA + mf * 512 + cA);
#define MFMA16(p)                                                             \
  __builtin_amdgcn_s_setprio(1);                                              \
  _Pragma("unroll")                                                           \
  for (int mf = 0; mf < 8; ++mf) {                                            \
    acc[mf][((p) & 1) * 2]     = MFMA(af[mf], bP[p][0], acc[mf][((p) & 1) * 2], 0, 0, 0);     \
    acc[mf][((p) & 1) * 2 + 1] = MFMA(af[mf], bP[p][1], acc[mf][((p) & 1) * 2 + 1], 0, 0, 0); \
  }                                                                           \
  __builtin_amdgcn_s_setprio(0);
#define BAR() asm volatile("s_barrier" ::: "memory")

  // prologue: stage kt0, load kt0's B frags
  ISSUE_A(0);
  asm volatile("s_waitcnt vmcnt(0)" ::: "memory");
  WRITE_A(Ls);
  LOAD_BP(0, 0); LOAD_BP(1, 0); LOAD_BP(2, 0); LOAD_BP(3, 0);
  asm volatile("s_waitcnt lgkmcnt(0)" ::: "memory");
  BAR();

  for (int kt = 0; kt < 8; ++kt) {
    const short* buf = Ls + (kt & 1) * 16384;
    short* nb = Ls + ((kt & 1) ^ 1) * 16384;

    LOAD_AF(buf, 0);
    if (kt < 7) ISSUE_A(kt + 1);        // 8 (or 4) HBM loads, in flight ~3.5 phases
    MFMA16(0);
    MFMA16(1);
    LOAD_AF(buf, 1);
    if (kt < 7) { LOAD_BP(0, kt + 1); LOAD_BP(1, kt + 1); }
    MFMA16(2);
    if (kt < 7) {
      asm volatile("s_waitcnt vmcnt(4)" ::: "memory");   // drain gA, keep bP01'
      WRITE_A(nb);
    }
    MFMA16(3);
    if (kt < 7) { LOAD_BP(2, kt + 1); LOAD_BP(3, kt + 1); }
    asm volatile("s_waitcnt lgkmcnt(0)" ::: "memory");   // ds_writes retired
    BAR();                                               // sole barrier per K-tile
  }

  if (EPI == 0) {
    __syncthreads();   // Ls free for full 256x256 bounce tile
#pragma unroll
    for (int mf = 0; mf < 8; ++mf)
#pragma unroll
      for (int r = 0; r < 4; ++r) {
        int lrow = wr * 128 + mf * 16 + g4 + r;
#pragma unroll
        for (int nf = 0; nf < 4; ++nf) {
          int lcol = wc * 64 + nf * 16 + l15;
          Ls[lrow * 256 + lcol] = f2bf(acc[mf][nf][r] + bias[n0 + lcol]);
        }
      }
    __syncthreads();
    short* qkv = (short*)outp;
    const int cq = n0 >> 8;          // 0..5
    const int ii = cq >> 1;
#pragma unroll
    for (int s = 0; s < 16; ++s) {
      int c = s * 512 + t;
      int row = c >> 5, sub = c & 31;
      int hl = sub >> 2, d0 = (sub & 3) * 8;
      int rg = (int)m0 + row;
      int b = rg / 49, n = rg - b * 49;
      int h = (cq & 1) * 8 + hl;
      long dst = (long)((b * 16 + h) * 3 + ii) * 1568 + n * 32 + d0;
      *(bf16x8*)(qkv + dst) = *(const bf16x8*)(Ls + row * 256 + hl * 32 + d0);
    }
  } else {
    float* out = (float*)outp;
#pragma unroll
    for (int mf = 0; mf < 8; ++mf)
#pragma unroll
      for (int r = 0; r < 4; ++r) {
        long row = m0 + wr * 128 + mf * 16 + g4 + r;
#pragma unroll
        for (int nf = 0; nf < 4; ++nf) {
          int col = n0 + wc * 64 + nf * 16 + l15;
          out[row * 512 + col] = acc[mf][nf][r] + bias[col];
        }
      }
  }
#undef ISSUE_A
#undef WRITE_A
#undef LOAD_BP
#undef LOAD_AF
#undef MFMA16
#undef BAR
}

// ---------------- attention: swapped-QK^T, in-register softmax (r9-verified) ----------------

__global__ __launch_bounds__(256, 3)
void attn49(const short* __restrict__ qkvb, const float* __restrict__ biasT,
            short* __restrict__ ao) {
  __shared__ short Vl[4][2048];

  const int t = threadIdx.x, lane = t & 63, wv = t >> 6;
  const int l15 = lane & 15, g = lane >> 4, g4 = g * 4;
  const int b = blockIdx.x >> 2;
  const int h = (blockIdx.x & 3) * 4 + wv;

  const short* qb = qkvb + (long)(b * 16 + h) * 3 * 1568;
  const short* kb = qb + 1568;
  const short* vb = kb + 1568;
  short* Vs = Vl[wv];

#pragma unroll
  for (int it = 0; it < 4; ++it) {
    int c = it * 64 + lane; c = c > 195 ? 195 : c;
    *(bf16x8*)(Vs + c * 8) = *(const bf16x8*)(vb + c * 8);
  }

  bf16x8 qf[4], kf[4];
#pragma unroll
  for (int i = 0; i < 4; ++i) {
    int row = i * 16 + l15; row = row > 48 ? 48 : row;
    kf[i] = *(const bf16x8*)(kb + row * 32 + g * 8);
    qf[i] = *(const bf16x8*)(qb + row * 32 + g * 8);
  }

  f32x4 s[4][4] = {};
#pragma unroll
  for (int i = 0; i < 4; ++i)
#pragma unroll
    for (int j = 0; j < 4; ++j)
      s[i][j] = MFMA(kf[i], qf[j], s[i][j], 0, 0, 0);

  bf16x8 vf[2][2];
#pragma unroll
  for (int kt = 0; kt < 2; ++kt)
#pragma unroll
    for (int hi = 0; hi < 2; ++hi)
#pragma unroll
      for (int r = 0; r < 4; ++r) {
        int m = kt * 32 + hi * 16 + g4 + r;
        m = m > 48 ? 48 : m;
#pragma unroll
        for (int dt = 0; dt < 2; ++dt)
          vf[kt][dt][hi * 4 + r] = Vs[m * 32 + dt * 16 + l15];
      }

  const float* biasH = biasT + h * 4096;
  float sum[4] = {0.f, 0.f, 0.f, 0.f};
#pragma unroll
  for (int i = 0; i < 4; ++i)
#pragma unroll
    for (int r = 0; r < 4; ++r) {
      int m = i * 16 + g4 + r;
      const float* bp = biasH + m * 64 + l15;
#pragma unroll
      for (int j = 0; j < 4; ++j) {
        float p = exp2a(fmaf(s[i][j][r], 0.06375871f, bp[j * 16]));
        s[i][j][r] = p;
        sum[j] += p;
      }
    }
#pragma unroll
  for (int j = 0; j < 4; ++j) {
    sum[j] += __shfl_xor(sum[j], 16);
    sum[j] += __shfl_xor(sum[j], 32);
    sum[j] = 1.f / sum[j];
  }

  unsigned pk[4][4][2];
#pragma unroll
  for (int j = 0; j < 4; ++j)
#pragma unroll
    for (int i = 0; i < 4; ++i) {
      pk[j][i][0] = pk2(s[i][j][0] * sum[j], s[i][j][1] * sum[j]);
      pk[j][i][1] = pk2(s[i][j][2] * sum[j], s[i][j][3] * sum[j]);
    }

  f32x4 o[4][2] = {};
#pragma unroll
  for (int j = 0; j < 4; ++j) {
    bf16x8 a0 = mk8(pk[j][0][0], pk[j][0][1], pk[j][1][0], pk[j][1][1]);
    bf16x8 a1 = mk8(pk[j][2][0], pk[j][2][1], pk[j][3][0], pk[j][3][1]);
    o[j][0] = MFMA(a0, vf[0][0], o[j][0], 0, 0, 0);
    o[j][0] = MFMA(a1, vf[1][0], o[j][0], 0, 0, 0);
    o[j][1] = MFMA(a0, vf[0][1], o[j][1], 0, 0, 0);
    o[j][1] = MFMA(a1, vf[1][1], o[j][1], 0, 0, 0);
  }

#pragma unroll
  for (int j = 0; j < 4; ++j)
#pragma unroll
    for (int r = 0; r < 4; ++r) {
      int n = j * 16 + g4 + r;
      if (n < 49) {
        long off = ((long)b * 49 + n) * 512 + h * 32 + l15;
        ao[off]      = f2bf(o[j][0][r]);
        ao[off + 16] = f2bf(o[j][1][r]);
      }
    }
}

// ---------------- host ----------------

extern "C" void kernel_launch(void* const* d_in, const int* in_sizes, int n_in,
                              void* d_out, int out_size, void* d_ws, size_t ws_size,
                              hipStream_t stream) {
  (void)in_sizes; (void)n_in; (void)ws_size;
  const float* x      = (const float*)d_in[0];
  const float* w_qkv  = (const float*)d_in[1];
  const float* b_qkv  = (const float*)d_in[2];
  const float* w_proj = (const float*)d_in[3];
  const float* b_proj = (const float*)d_in[4];
  const float* btab   = (const float*)d_in[5];

  char* ws = (char*)d_ws;
  short* wqP = (short*)ws;                                   //   1,572,864 B
  short* wpP = (short*)(ws + 1572864L);                      //     524,288 B
  short* qkv = (short*)(ws + 2097152L);                      // 616,562,688 B
  short* ao  = (short*)(ws + 2097152L + 616562688L);         // 205,520,896 B
  // biasT in d_out tail: written by prep_k, read by attn49, fully overwritten by proj.
  float* biasT = (float*)d_out + (out_size - 65536);

  prep_k<<<4352, 256, 0, stream>>>(w_qkv, w_proj, btab, wqP, wpP, biasT);
  gemm256<0, true><<<4704, 512, 0, stream>>>(x, wqP, b_qkv, (void*)qkv, 6);
  attn49<<<16384, 256, 0, stream>>>(qkv, biasT, ao);
  gemm256<1, false><<<1568, 512, 0, stream>>>(ao, wpP, b_proj, d_out, 2);
}

// Round 15
// 851.438 us; speedup vs baseline: 2.0088x; 1.0026x over previous
//
#include <hip/hip_runtime.h>
#include <hip/hip_bf16.h>

typedef __attribute__((ext_vector_type(8))) short bf16x8;
typedef __attribute__((ext_vector_type(4))) float f32x4;

#define DEVI __device__ __forceinline__
#define MFMA __builtin_amdgcn_mfma_f32_16x16x32_bf16

DEVI short f2bf(float f) {
  union { float f; unsigned u; } v; v.f = f;
  unsigned r = v.u + 0x7FFFu + ((v.u >> 16) & 1u);
  return (short)(r >> 16);
}

DEVI float exp2a(float x) { float r; asm("v_exp_f32 %0, %1" : "=v"(r) : "v"(x)); return r; }

DEVI unsigned pk2(float lo, float hi) {
  union { __hip_bfloat162 h; unsigned u; } v;
  float2 f; f.x = lo; f.y = hi;
  v.h = __float22bfloat162_rn(f);
  return v.u;
}

union U8 { unsigned u[4]; bf16x8 v; };
DEVI bf16x8 mk8(unsigned a, unsigned b, unsigned c, unsigned d) {
  U8 x; x.u[0]=a; x.u[1]=b; x.u[2]=c; x.u[3]=d; return x.v;
}

// ---------------- prep: fragment-linear weight packs + biasT ----------------
// wqP[((cf*16+kc)*512 + lane*8 + e] = bf16(wq[k][col]); k = kc*32+(lane>>4)*8+e,
// col = cf*16+(lane&15).  wpP same from w_proj.  biasT as before.
__global__ __launch_bounds__(256) void prep_k(const float* __restrict__ wq,
                                              const float* __restrict__ wp,
                                              const float* __restrict__ btab,
                                              short* __restrict__ wqP,
                                              short* __restrict__ wpP,
                                              float* __restrict__ biasT) {
  int bid = blockIdx.x;
  if (bid < 4096) {
    int i = (bid < 3072 ? bid : bid - 3072) * 256 + threadIdx.x;
    int e = i & 7, lane = (i >> 3) & 63, kc = (i >> 9) & 15, cf = i >> 13;
    int k = kc * 32 + (lane >> 4) * 8 + e;
    int col = cf * 16 + (lane & 15);
    if (bid < 3072) wqP[i] = f2bf(wq[k * 1536 + col]);
    else            wpP[i] = f2bf(wp[k * 512 + col]);
  } else {
    int i = (bid - 4096) * 256 + threadIdx.x;   // 16*64*64
    int h = i >> 12, m = (i >> 6) & 63, n = i & 63;
    float v;
    if (m >= 49) {
      v = -1e30f;
    } else {
      int nn = n > 48 ? 48 : n;
      int ni = nn / 7, nj = nn - ni * 7;
      int mi = m / 7,  mj = m - mi * 7;
      int idx = (ni - mi + 6) * 13 + (nj - mj + 6);
      v = btab[idx * 16 + h] * 1.4426950408889634f;
    }
    biasT[i] = v;
  }
}

// ---------------- 256x256 bf16 GEMM: A reg-staged (opt. fp32->bf16 fused), ----------------
// B-frags direct from packed global (L1/L2-resident), LDS holds A only (64KB dbuf).
// One barrier per K-tile; per-load compiler vmcnt waits keep staging in flight.

template <int EPI, bool AF32>
__global__ __launch_bounds__(512)
void gemm256(const void* __restrict__ Ap, const short* __restrict__ wB,
             const float* __restrict__ bias, void* __restrict__ outp, int ctiles) {
  __shared__ short Ls[65536];   // K-loop: [2][16384] A dbuf; EPI0 epilogue: full 128KB

  const int nwg = gridDim.x;
  const int w = blockIdx.x;
  const int chunk = nwg >> 3;
  const int tid = (w & 7) * chunk + (w >> 3);    // XCD-contiguous remap (nwg%8==0)
  const int rt = tid / ctiles, ct = tid % ctiles;
  const long m0 = (long)rt * 256;
  const int n0 = ct * 256;

  const int t = threadIdx.x;          // 0..511
  const int lane = t & 63;
  const int wv = t >> 6;
  const int wr = wv >> 2;             // M half
  const int wc = wv & 3;              // N quarter
  const int l15 = lane & 15, g = lane >> 4, g4 = g * 4;

  // A staging: thread t -> LDS row t>>2 (+128), 16B slot t&3, global chunk swizzled
  const int gch = (t & 3) ^ ((t >> 3) & 3);
  const float* Agf = (const float*)Ap + (m0 + (t >> 2)) * 512 + gch * 8;
  const short* Agh = (const short*)Ap + (m0 + (t >> 2)) * 512 + gch * 8;

  const int cA = (g ^ ((l15 >> 1) & 3)) * 8;
  const int rowA = (wr * 128 + l15) * 32;

  // B frags: cf = ct*16 + wc*4 + nf ; addr = wB + (cf*16 + kc)*512 + lane*8
  const short* wBb = wB + ((long)(ct * 16 + wc * 4) << 13) + lane * 8;

  f32x4 acc[8][4] = {};
  bf16x8 af[8];
  bf16x8 bP[4][2];
  float4 ga[4][2];
  bf16x8 gb[4];

#define ISSUE_A(ktn)                                                          \
  if (AF32) {                                                                 \
    _Pragma("unroll")                                                         \
    for (int c = 0; c < 4; ++c) {                                             \
      const float* s_ = Agf + (c >> 1) * 65536 + (c & 1) * 32 + (ktn) * 64;   \
      ga[c][0] = *(const float4*)s_;                                          \
      ga[c][1] = *(const float4*)(s_ + 4);                                    \
    }                                                                         \
  } else {                                                                    \
    _Pragma("unroll")                                                         \
    for (int c = 0; c < 4; ++c)                                               \
      gb[c] = *(const bf16x8*)(Agh + (c >> 1) * 65536 + (c & 1) * 32 + (ktn) * 64); \
  }
#define WRITE_A(nb)                                                           \
  _Pragma("unroll")                                                           \
  for (int c = 0; c < 4; ++c) {                                               \
    short* d_ = (nb) + (c & 1) * 8192 + (c >> 1) * 4096 + t * 8;              \
    if (AF32) {                                                               \
      *(bf16x8*)d_ = mk8(pk2(ga[c][0].x, ga[c][0].y), pk2(ga[c][0].z, ga[c][0].w), \
                         pk2(ga[c][1].x, ga[c][1].y), pk2(ga[c][1].z, ga[c][1].w)); \
    } else {                                                                  \
      *(bf16x8*)d_ = gb[c];                                                   \
    }                                                                         \
  }
#define LOAD_BP(p, ktn)                                                       \
  bP[p][0] = *(const bf16x8*)(wBb + ((((((p) & 1) * 2 + 0) * 16 + ((ktn) * 2 + ((p) >> 1)))) << 9)); \
  bP[p][1] = *(const bf16x8*)(wBb + ((((((p) & 1) * 2 + 1) * 16 + ((ktn) * 2 + ((p) >> 1)))) << 9));
#define LOAD_AF(buf, kh)                                                      \
  _Pragma("unroll")                                                           \
  for (int mf = 0; mf < 8; ++mf)                                              \
    af[mf] = *(const bf16x8*)((buf) + (kh) * 8192 + rowA + mf * 512 + cA);
#define MFMA16(p)                                                             \
  __builtin_amdgcn_s_setprio(1);                                              \
  _Pragma("unroll")                                                           \
  for (int mf = 0; mf < 8; ++mf) {                                            \
    acc[mf][((p) & 1) * 2]     = MFMA(af[mf], bP[p][0], acc[mf][((p) & 1) * 2], 0, 0, 0);     \
    acc[mf][((p) & 1) * 2 + 1] = MFMA(af[mf], bP[p][1], acc[mf][((p) & 1) * 2 + 1], 0, 0, 0); \
  }                                                                           \
  __builtin_amdgcn_s_setprio(0);
#define BAR() asm volatile("s_barrier" ::: "memory")

  // prologue: stage kt0, load kt0's B frags
  ISSUE_A(0);
  asm volatile("s_waitcnt vmcnt(0)" ::: "memory");
  WRITE_A(Ls);
  LOAD_BP(0, 0); LOAD_BP(1, 0); LOAD_BP(2, 0); LOAD_BP(3, 0);
  asm volatile("s_waitcnt lgkmcnt(0)" ::: "memory");
  BAR();

  for (int kt = 0; kt < 8; ++kt) {
    const short* buf = Ls + (kt & 1) * 16384;
    short* nb = Ls + ((kt & 1) ^ 1) * 16384;

    LOAD_AF(buf, 0);
    if (kt < 7) ISSUE_A(kt + 1);        // 8 (or 4) HBM loads, in flight ~3.5 phases
    MFMA16(0);
    MFMA16(1);
    LOAD_AF(buf, 1);
    if (kt < 7) { LOAD_BP(0, kt + 1); LOAD_BP(1, kt + 1); }
    MFMA16(2);
    if (kt < 7) {
      asm volatile("s_waitcnt vmcnt(4)" ::: "memory");   // drain gA, keep bP01'
      WRITE_A(nb);
    }
    MFMA16(3);
    if (kt < 7) { LOAD_BP(2, kt + 1); LOAD_BP(3, kt + 1); }
    asm volatile("s_waitcnt lgkmcnt(0)" ::: "memory");   // ds_writes retired
    BAR();                                               // sole barrier per K-tile
  }

  if (EPI == 0) {
    __syncthreads();   // Ls free for full 256x256 bounce tile
#pragma unroll
    for (int mf = 0; mf < 8; ++mf)
#pragma unroll
      for (int r = 0; r < 4; ++r) {
        int lrow = wr * 128 + mf * 16 + g4 + r;
#pragma unroll
        for (int nf = 0; nf < 4; ++nf) {
          int lcol = wc * 64 + nf * 16 + l15;
          Ls[lrow * 256 + lcol] = f2bf(acc[mf][nf][r] + bias[n0 + lcol]);
        }
      }
    __syncthreads();
    short* qkv = (short*)outp;
    const int cq = n0 >> 8;          // 0..5
    const int ii = cq >> 1;
#pragma unroll
    for (int s = 0; s < 16; ++s) {
      int c = s * 512 + t;
      int row = c >> 5, sub = c & 31;
      int hl = sub >> 2, d0 = (sub & 3) * 8;
      int rg = (int)m0 + row;
      int b = rg / 49, n = rg - b * 49;
      int h = (cq & 1) * 8 + hl;
      long dst = (long)((b * 16 + h) * 3 + ii) * 1568 + n * 32 + d0;
      *(bf16x8*)(qkv + dst) = *(const bf16x8*)(Ls + row * 256 + hl * 32 + d0);
    }
  } else {
    float* out = (float*)outp;
#pragma unroll
    for (int mf = 0; mf < 8; ++mf)
#pragma unroll
      for (int r = 0; r < 4; ++r) {
        long row = m0 + wr * 128 + mf * 16 + g4 + r;
#pragma unroll
        for (int nf = 0; nf < 4; ++nf) {
          int col = n0 + wc * 64 + nf * 16 + l15;
          out[row * 512 + col] = acc[mf][nf][r] + bias[col];
        }
      }
  }
#undef ISSUE_A
#undef WRITE_A
#undef LOAD_BP
#undef LOAD_AF
#undef MFMA16
#undef BAR
}

// ---------------- attention: swapped-QK^T, in-register softmax (r9-verified) ----------------

__global__ __launch_bounds__(256, 3)
void attn49(const short* __restrict__ qkvb, const float* __restrict__ biasT,
            short* __restrict__ ao) {
  __shared__ short Vl[4][2048];

  const int t = threadIdx.x, lane = t & 63, wv = t >> 6;
  const int l15 = lane & 15, g = lane >> 4, g4 = g * 4;
  const int b = blockIdx.x >> 2;
  const int h = (blockIdx.x & 3) * 4 + wv;

  const short* qb = qkvb + (long)(b * 16 + h) * 3 * 1568;
  const short* kb = qb + 1568;
  const short* vb = kb + 1568;
  short* Vs = Vl[wv];

#pragma unroll
  for (int it = 0; it < 4; ++it) {
    int c = it * 64 + lane; c = c > 195 ? 195 : c;
    *(bf16x8*)(Vs + c * 8) = *(const bf16x8*)(vb + c * 8);
  }

  bf16x8 qf[4], kf[4];
#pragma unroll
  for (int i = 0; i < 4; ++i) {
    int row = i * 16 + l15; row = row > 48 ? 48 : row;
    kf[i] = *(const bf16x8*)(kb + row * 32 + g * 8);
    qf[i] = *(const bf16x8*)(qb + row * 32 + g * 8);
  }

  f32x4 s[4][4] = {};
#pragma unroll
  for (int i = 0; i < 4; ++i)
#pragma unroll
    for (int j = 0; j < 4; ++j)
      s[i][j] = MFMA(kf[i], qf[j], s[i][j], 0, 0, 0);

  bf16x8 vf[2][2];
#pragma unroll
  for (int kt = 0; kt < 2; ++kt)
#pragma unroll
    for (int hi = 0; hi < 2; ++hi)
#pragma unroll
      for (int r = 0; r < 4; ++r) {
        int m = kt * 32 + hi * 16 + g4 + r;
        m = m > 48 ? 48 : m;
#pragma unroll
        for (int dt = 0; dt < 2; ++dt)
          vf[kt][dt][hi * 4 + r] = Vs[m * 32 + dt * 16 + l15];
      }

  const float* biasH = biasT + h * 4096;
  float sum[4] = {0.f, 0.f, 0.f, 0.f};
#pragma unroll
  for (int i = 0; i < 4; ++i)
#pragma unroll
    for (int r = 0; r < 4; ++r) {
      int m = i * 16 + g4 + r;
      const float* bp = biasH + m * 64 + l15;
#pragma unroll
      for (int j = 0; j < 4; ++j) {
        float p = exp2a(fmaf(s[i][j][r], 0.06375871f, bp[j * 16]));
        s[i][j][r] = p;
        sum[j] += p;
      }
    }
#pragma unroll
  for (int j = 0; j < 4; ++j) {
    sum[j] += __shfl_xor(sum[j], 16);
    sum[j] += __shfl_xor(sum[j], 32);
    sum[j] = 1.f / sum[j];
  }

  unsigned pk[4][4][2];
#pragma unroll
  for (int j = 0; j < 4; ++j)
#pragma unroll
    for (int i = 0; i < 4; ++i) {
      pk[j][i][0] = pk2(s[i][j][0] * sum[j], s[i][j][1] * sum[j]);
      pk[j][i][1] = pk2(s[i][j][2] * sum[j], s[i][j][3] * sum[j]);
    }

  f32x4 o[4][2] = {};
#pragma unroll
  for (int j = 0; j < 4; ++j) {
    bf16x8 a0 = mk8(pk[j][0][0], pk[j][0][1], pk[j][1][0], pk[j][1][1]);
    bf16x8 a1 = mk8(pk[j][2][0], pk[j][2][1], pk[j][3][0], pk[j][3][1]);
    o[j][0] = MFMA(a0, vf[0][0], o[j][0], 0, 0, 0);
    o[j][0] = MFMA(a1, vf[1][0], o[j][0], 0, 0, 0);
    o[j][1] = MFMA(a0, vf[0][1], o[j][1], 0, 0, 0);
    o[j][1] = MFMA(a1, vf[1][1], o[j][1], 0, 0, 0);
  }

#pragma unroll
  for (int j = 0; j < 4; ++j)
#pragma unroll
    for (int r = 0; r < 4; ++r) {
      int n = j * 16 + g4 + r;
      if (n < 49) {
        long off = ((long)b * 49 + n) * 512 + h * 32 + l15;
        ao[off]      = f2bf(o[j][0][r]);
        ao[off + 16] = f2bf(o[j][1][r]);
      }
    }
}

// ---------------- host ----------------

extern "C" void kernel_launch(void* const* d_in, const int* in_sizes, int n_in,
                              void* d_out, int out_size, void* d_ws, size_t ws_size,
                              hipStream_t stream) {
  (void)in_sizes; (void)n_in; (void)ws_size;
  const float* x      = (const float*)d_in[0];
  const float* w_qkv  = (const float*)d_in[1];
  const float* b_qkv  = (const float*)d_in[2];
  const float* w_proj = (const float*)d_in[3];
  const float* b_proj = (const float*)d_in[4];
  const float* btab   = (const float*)d_in[5];

  char* ws = (char*)d_ws;
  short* wqP = (short*)ws;                                   //   1,572,864 B
  short* wpP = (short*)(ws + 1572864L);                      //     524,288 B
  short* qkv = (short*)(ws + 2097152L);                      // 616,562,688 B
  short* ao  = (short*)(ws + 2097152L + 616562688L);         // 205,520,896 B
  // biasT in d_out tail: written by prep_k, read by attn49, fully overwritten by proj.
  float* biasT = (float*)d_out + (out_size - 65536);

  prep_k<<<4352, 256, 0, stream>>>(w_qkv, w_proj, btab, wqP, wpP, biasT);
  gemm256<0, true><<<4704, 512, 0, stream>>>(x, wqP, b_qkv, (void*)qkv, 6);
  attn49<<<16384, 256, 0, stream>>>(qkv, biasT, ao);
  gemm256<1, false><<<1568, 512, 0, stream>>>(ao, wpP, b_proj, d_out, 2);
}

// Round 16
// 833.146 us; speedup vs baseline: 2.0529x; 1.0220x over previous
//
#include <hip/hip_runtime.h>
#include <hip/hip_bf16.h>

typedef __attribute__((ext_vector_type(8))) short bf16x8;
typedef __attribute__((ext_vector_type(4))) float f32x4;

#define DEVI __device__ __forceinline__
#define MFMA __builtin_amdgcn_mfma_f32_16x16x32_bf16

DEVI short f2bf(float f) {
  union { float f; unsigned u; } v; v.f = f;
  unsigned r = v.u + 0x7FFFu + ((v.u >> 16) & 1u);
  return (short)(r >> 16);
}

DEVI float exp2a(float x) { float r; asm("v_exp_f32 %0, %1" : "=v"(r) : "v"(x)); return r; }

DEVI unsigned pk2(float lo, float hi) {
  union { __hip_bfloat162 h; unsigned u; } v;
  float2 f; f.x = lo; f.y = hi;
  v.h = __float22bfloat162_rn(f);
  return v.u;
}

union U8 { unsigned u[4]; bf16x8 v; };
DEVI bf16x8 mk8(unsigned a, unsigned b, unsigned c, unsigned d) {
  U8 x; x.u[0]=a; x.u[1]=b; x.u[2]=c; x.u[3]=d; return x.v;
}

// ---------------- prep: fragment-linear weight packs + biasT ----------------
// wqP[((cf*16+kc)*512 + lane*8 + e] = bf16(wq[k][col]); k = kc*32+(lane>>4)*8+e,
// col = cf*16+(lane&15).  wpP same from w_proj.  biasT as before.
__global__ __launch_bounds__(256) void prep_k(const float* __restrict__ wq,
                                              const float* __restrict__ wp,
                                              const float* __restrict__ btab,
                                              short* __restrict__ wqP,
                                              short* __restrict__ wpP,
                                              float* __restrict__ biasT) {
  int bid = blockIdx.x;
  if (bid < 4096) {
    int i = (bid < 3072 ? bid : bid - 3072) * 256 + threadIdx.x;
    int e = i & 7, lane = (i >> 3) & 63, kc = (i >> 9) & 15, cf = i >> 13;
    int k = kc * 32 + (lane >> 4) * 8 + e;
    int col = cf * 16 + (lane & 15);
    if (bid < 3072) wqP[i] = f2bf(wq[k * 1536 + col]);
    else            wpP[i] = f2bf(wp[k * 512 + col]);
  } else {
    int i = (bid - 4096) * 256 + threadIdx.x;   // 16*64*64
    int h = i >> 12, m = (i >> 6) & 63, n = i & 63;
    float v;
    if (m >= 49) {
      v = -1e30f;
    } else {
      int nn = n > 48 ? 48 : n;
      int ni = nn / 7, nj = nn - ni * 7;
      int mi = m / 7,  mj = m - mi * 7;
      int idx = (ni - mi + 6) * 13 + (nj - mj + 6);
      v = btab[idx * 16 + h] * 1.4426950408889634f;
    }
    biasT[i] = v;
  }
}

// ---------------- 256x256 bf16 GEMM: A reg-staged (opt. fp32->bf16 fused), ----------------
// B-frags direct from packed global (L1/L2-resident), LDS holds A only (64KB dbuf).
// r16 delta vs r15: A issued one full K-tile ahead (ISSUE_A(kt+2) right after WRITE_A
// consumes ga) -> HBM latency fully covered. All ga/bP waits are compiler-tracked.

template <int EPI, bool AF32>
__global__ __launch_bounds__(512)
void gemm256(const void* __restrict__ Ap, const short* __restrict__ wB,
             const float* __restrict__ bias, void* __restrict__ outp, int ctiles) {
  __shared__ short Ls[65536];   // K-loop: [2][16384] A dbuf; EPI0 epilogue: full 128KB

  const int nwg = gridDim.x;
  const int w = blockIdx.x;
  const int chunk = nwg >> 3;
  const int tid = (w & 7) * chunk + (w >> 3);    // XCD-contiguous remap (nwg%8==0)
  const int rt = tid / ctiles, ct = tid % ctiles;
  const long m0 = (long)rt * 256;
  const int n0 = ct * 256;

  const int t = threadIdx.x;          // 0..511
  const int lane = t & 63;
  const int wv = t >> 6;
  const int wr = wv >> 2;             // M half
  const int wc = wv & 3;              // N quarter
  const int l15 = lane & 15, g = lane >> 4, g4 = g * 4;

  // A staging: thread t -> LDS row t>>2 (+128), 16B slot t&3, global chunk swizzled
  const int gch = (t & 3) ^ ((t >> 3) & 3);
  const float* Agf = (const float*)Ap + (m0 + (t >> 2)) * 512 + gch * 8;
  const short* Agh = (const short*)Ap + (m0 + (t >> 2)) * 512 + gch * 8;

  const int cA = (g ^ ((l15 >> 1) & 3)) * 8;
  const int rowA = (wr * 128 + l15) * 32;

  // B frags: cf = ct*16 + wc*4 + nf ; addr = wB + (cf*16 + kc)*512 + lane*8
  const short* wBb = wB + ((long)(ct * 16 + wc * 4) << 13) + lane * 8;

  f32x4 acc[8][4] = {};
  bf16x8 af[8];
  bf16x8 bP[4][2];
  float4 ga[4][2];
  bf16x8 gb[4];

#define ISSUE_A(ktn)                                                          \
  if (AF32) {                                                                 \
    _Pragma("unroll")                                                         \
    for (int c = 0; c < 4; ++c) {                                             \
      const float* s_ = Agf + (c >> 1) * 65536 + (c & 1) * 32 + (ktn) * 64;   \
      ga[c][0] = *(const float4*)s_;                                          \
      ga[c][1] = *(const float4*)(s_ + 4);                                    \
    }                                                                         \
  } else {                                                                    \
    _Pragma("unroll")                                                         \
    for (int c = 0; c < 4; ++c)                                               \
      gb[c] = *(const bf16x8*)(Agh + (c >> 1) * 65536 + (c & 1) * 32 + (ktn) * 64); \
  }
#define WRITE_A(nb)                                                           \
  _Pragma("unroll")                                                           \
  for (int c = 0; c < 4; ++c) {                                               \
    short* d_ = (nb) + (c & 1) * 8192 + (c >> 1) * 4096 + t * 8;              \
    if (AF32) {                                                               \
      *(bf16x8*)d_ = mk8(pk2(ga[c][0].x, ga[c][0].y), pk2(ga[c][0].z, ga[c][0].w), \
                         pk2(ga[c][1].x, ga[c][1].y), pk2(ga[c][1].z, ga[c][1].w)); \
    } else {                                                                  \
      *(bf16x8*)d_ = gb[c];                                                   \
    }                                                                         \
  }
#define LOAD_BP(p, ktn)                                                       \
  bP[p][0] = *(const bf16x8*)(wBb + ((((((p) & 1) * 2 + 0) * 16 + ((ktn) * 2 + ((p) >> 1)))) << 9)); \
  bP[p][1] = *(const bf16x8*)(wBb + ((((((p) & 1) * 2 + 1) * 16 + ((ktn) * 2 + ((p) >> 1)))) << 9));
#define LOAD_AF(buf, kh)                                                      \
  _Pragma("unroll")                                                           \
  for (int mf = 0; mf < 8; ++mf)                                              \
    af[mf] = *(const bf16x8*)((buf) + (kh) * 8192 + rowA + mf * 512 + cA);
#define MFMA16(p)                                                             \
  __builtin_amdgcn_s_setprio(1);                                              \
  _Pragma("unroll")                                                           \
  for (int mf = 0; mf < 8; ++mf) {                                            \
    acc[mf][((p) & 1) * 2]     = MFMA(af[mf], bP[p][0], acc[mf][((p) & 1) * 2], 0, 0, 0);     \
    acc[mf][((p) & 1) * 2 + 1] = MFMA(af[mf], bP[p][1], acc[mf][((p) & 1) * 2 + 1], 0, 0, 0); \
  }                                                                           \
  __builtin_amdgcn_s_setprio(0);
#define BAR() asm volatile("s_barrier" ::: "memory")

  // prologue: stage kt0; issue kt1's A early; load kt0's B frags
  ISSUE_A(0);
  asm volatile("s_waitcnt vmcnt(0)" ::: "memory");
  WRITE_A(Ls);
  ISSUE_A(1);
  LOAD_BP(0, 0); LOAD_BP(1, 0); LOAD_BP(2, 0); LOAD_BP(3, 0);
  asm volatile("s_waitcnt lgkmcnt(0)" ::: "memory");
  BAR();

  for (int kt = 0; kt < 8; ++kt) {
    const short* buf = Ls + (kt & 1) * 16384;
    short* nb = Ls + ((kt & 1) ^ 1) * 16384;

    LOAD_AF(buf, 0);
    MFMA16(0);
    MFMA16(1);
    LOAD_AF(buf, 1);
    if (kt < 7) { LOAD_BP(0, kt + 1); LOAD_BP(1, kt + 1); }
    MFMA16(2);
    if (kt < 7) {
      asm volatile("s_waitcnt vmcnt(4)" ::: "memory");   // drain A(kt+1), keep bP01'
      WRITE_A(nb);                                       // A(kt+1) -> other buf
      if (kt < 6) ISSUE_A(kt + 2);                       // full K-tile of latency cover
    }
    MFMA16(3);
    if (kt < 7) { LOAD_BP(2, kt + 1); LOAD_BP(3, kt + 1); }
    asm volatile("s_waitcnt lgkmcnt(0)" ::: "memory");   // ds_writes retired
    BAR();                                               // sole barrier per K-tile
  }

  if (EPI == 0) {
    __syncthreads();   // Ls free for full 256x256 bounce tile
#pragma unroll
    for (int mf = 0; mf < 8; ++mf)
#pragma unroll
      for (int r = 0; r < 4; ++r) {
        int lrow = wr * 128 + mf * 16 + g4 + r;
#pragma unroll
        for (int nf = 0; nf < 4; ++nf) {
          int lcol = wc * 64 + nf * 16 + l15;
          Ls[lrow * 256 + lcol] = f2bf(acc[mf][nf][r] + bias[n0 + lcol]);
        }
      }
    __syncthreads();
    short* qkv = (short*)outp;
    const int cq = n0 >> 8;          // 0..5
    const int ii = cq >> 1;
#pragma unroll
    for (int s = 0; s < 16; ++s) {
      int c = s * 512 + t;
      int row = c >> 5, sub = c & 31;
      int hl = sub >> 2, d0 = (sub & 3) * 8;
      int rg = (int)m0 + row;
      int b = rg / 49, n = rg - b * 49;
      int h = (cq & 1) * 8 + hl;
      long dst = (long)((b * 16 + h) * 3 + ii) * 1568 + n * 32 + d0;
      *(bf16x8*)(qkv + dst) = *(const bf16x8*)(Ls + row * 256 + hl * 32 + d0);
    }
  } else {
    float* out = (float*)outp;
#pragma unroll
    for (int mf = 0; mf < 8; ++mf)
#pragma unroll
      for (int r = 0; r < 4; ++r) {
        long row = m0 + wr * 128 + mf * 16 + g4 + r;
#pragma unroll
        for (int nf = 0; nf < 4; ++nf) {
          int col = n0 + wc * 64 + nf * 16 + l15;
          out[row * 512 + col] = acc[mf][nf][r] + bias[col];
        }
      }
  }
#undef ISSUE_A
#undef WRITE_A
#undef LOAD_BP
#undef LOAD_AF
#undef MFMA16
#undef BAR
}

// ---------------- attention: swapped-QK^T, in-register softmax (r9-verified) ----------------

__global__ __launch_bounds__(256, 3)
void attn49(const short* __restrict__ qkvb, const float* __restrict__ biasT,
            short* __restrict__ ao) {
  __shared__ short Vl[4][2048];

  const int t = threadIdx.x, lane = t & 63, wv = t >> 6;
  const int l15 = lane & 15, g = lane >> 4, g4 = g * 4;
  const int b = blockIdx.x >> 2;
  const int h = (blockIdx.x & 3) * 4 + wv;

  const short* qb = qkvb + (long)(b * 16 + h) * 3 * 1568;
  const short* kb = qb + 1568;
  const short* vb = kb + 1568;
  short* Vs = Vl[wv];

#pragma unroll
  for (int it = 0; it < 4; ++it) {
    int c = it * 64 + lane; c = c > 195 ? 195 : c;
    *(bf16x8*)(Vs + c * 8) = *(const bf16x8*)(vb + c * 8);
  }

  bf16x8 qf[4], kf[4];
#pragma unroll
  for (int i = 0; i < 4; ++i) {
    int row = i * 16 + l15; row = row > 48 ? 48 : row;
    kf[i] = *(const bf16x8*)(kb + row * 32 + g * 8);
    qf[i] = *(const bf16x8*)(qb + row * 32 + g * 8);
  }

  f32x4 s[4][4] = {};
#pragma unroll
  for (int i = 0; i < 4; ++i)
#pragma unroll
    for (int j = 0; j < 4; ++j)
      s[i][j] = MFMA(kf[i], qf[j], s[i][j], 0, 0, 0);

  bf16x8 vf[2][2];
#pragma unroll
  for (int kt = 0; kt < 2; ++kt)
#pragma unroll
    for (int hi = 0; hi < 2; ++hi)
#pragma unroll
      for (int r = 0; r < 4; ++r) {
        int m = kt * 32 + hi * 16 + g4 + r;
        m = m > 48 ? 48 : m;
#pragma unroll
        for (int dt = 0; dt < 2; ++dt)
          vf[kt][dt][hi * 4 + r] = Vs[m * 32 + dt * 16 + l15];
      }

  const float* biasH = biasT + h * 4096;
  float sum[4] = {0.f, 0.f, 0.f, 0.f};
#pragma unroll
  for (int i = 0; i < 4; ++i)
#pragma unroll
    for (int r = 0; r < 4; ++r) {
      int m = i * 16 + g4 + r;
      const float* bp = biasH + m * 64 + l15;
#pragma unroll
      for (int j = 0; j < 4; ++j) {
        float p = exp2a(fmaf(s[i][j][r], 0.06375871f, bp[j * 16]));
        s[i][j][r] = p;
        sum[j] += p;
      }
    }
#pragma unroll
  for (int j = 0; j < 4; ++j) {
    sum[j] += __shfl_xor(sum[j], 16);
    sum[j] += __shfl_xor(sum[j], 32);
    sum[j] = 1.f / sum[j];
  }

  unsigned pk[4][4][2];
#pragma unroll
  for (int j = 0; j < 4; ++j)
#pragma unroll
    for (int i = 0; i < 4; ++i) {
      pk[j][i][0] = pk2(s[i][j][0] * sum[j], s[i][j][1] * sum[j]);
      pk[j][i][1] = pk2(s[i][j][2] * sum[j], s[i][j][3] * sum[j]);
    }

  f32x4 o[4][2] = {};
#pragma unroll
  for (int j = 0; j < 4; ++j) {
    bf16x8 a0 = mk8(pk[j][0][0], pk[j][0][1], pk[j][1][0], pk[j][1][1]);
    bf16x8 a1 = mk8(pk[j][2][0], pk[j][2][1], pk[j][3][0], pk[j][3][1]);
    o[j][0] = MFMA(a0, vf[0][0], o[j][0], 0, 0, 0);
    o[j][0] = MFMA(a1, vf[1][0], o[j][0], 0, 0, 0);
    o[j][1] = MFMA(a0, vf[0][1], o[j][1], 0, 0, 0);
    o[j][1] = MFMA(a1, vf[1][1], o[j][1], 0, 0, 0);
  }

#pragma unroll
  for (int j = 0; j < 4; ++j)
#pragma unroll
    for (int r = 0; r < 4; ++r) {
      int n = j * 16 + g4 + r;
      if (n < 49) {
        long off = ((long)b * 49 + n) * 512 + h * 32 + l15;
        ao[off]      = f2bf(o[j][0][r]);
        ao[off + 16] = f2bf(o[j][1][r]);
      }
    }
}

// ---------------- host ----------------

extern "C" void kernel_launch(void* const* d_in, const int* in_sizes, int n_in,
                              void* d_out, int out_size, void* d_ws, size_t ws_size,
                              hipStream_t stream) {
  (void)in_sizes; (void)n_in; (void)ws_size;
  const float* x      = (const float*)d_in[0];
  const float* w_qkv  = (const float*)d_in[1];
  const float* b_qkv  = (const float*)d_in[2];
  const float* w_proj = (const float*)d_in[3];
  const float* b_proj = (const float*)d_in[4];
  const float* btab   = (const float*)d_in[5];

  char* ws = (char*)d_ws;
  short* wqP = (short*)ws;                                   //   1,572,864 B
  short* wpP = (short*)(ws + 1572864L);                      //     524,288 B
  short* qkv = (short*)(ws + 2097152L);                      // 616,562,688 B
  short* ao  = (short*)(ws + 2097152L + 616562688L);         // 205,520,896 B
  // biasT in d_out tail: written by prep_k, read by attn49, fully overwritten by proj.
  float* biasT = (float*)d_out + (out_size - 65536);

  prep_k<<<4352, 256, 0, stream>>>(w_qkv, w_proj, btab, wqP, wpP, biasT);
  gemm256<0, true><<<4704, 512, 0, stream>>>(x, wqP, b_qkv, (void*)qkv, 6);
  attn49<<<16384, 256, 0, stream>>>(qkv, biasT, ao);
  gemm256<1, false><<<1568, 512, 0, stream>>>(ao, wpP, b_proj, d_out, 2);
}